// Round 1
// baseline (897.413 us; speedup 1.0000x reference)
//
#include <hip/hip_runtime.h>

// Problem constants
#define N_TOK 65536
#define DIM   256
#define KCODE 1024
#define MU_C    0.01f
#define EPS_C   1e-5f

// d_out offsets (floats), reference return order
#define O_Q    0
#define O_LOSS 16777216
#define O_IDX  16777217
#define O_PERP 16842753
#define O_NC   16842754
#define O_NEW  16843778
#define O_EMB  17105922

// d_ws offsets (floats)
#define W_IDX  0         // int[65536]
#define W_CNT  65536     // float[1024]
#define W_DW   66560     // float[262144]
#define W_WSQ  328704    // float[1024]
#define W_XSQ  329728    // float[65536]
#define W_ELAT 395264    // float[1]
// total ws use: 395265 floats = 1.59 MB

// ---------------------------------------------------------------- zero scratch
__global__ void zero_ws(float* __restrict__ ws) {
    int gid = blockIdx.x * blockDim.x + threadIdx.x;
    if (gid < 263168) ws[W_CNT + gid] = 0.0f;        // counts + dw
    else if (gid == 263168) ws[W_ELAT] = 0.0f;
}

// ------------------------------------------------- row sum-of-squares (W then X)
__global__ void sumsq_kernel(const float* __restrict__ W, const float* __restrict__ X,
                             float* __restrict__ wsq, float* __restrict__ xsq) {
    int wave = (blockIdx.x * blockDim.x + threadIdx.x) >> 6;   // one wave per row
    int lane = threadIdx.x & 63;
    if (wave >= KCODE + N_TOK) return;
    const float* row = (wave < KCODE) ? (W + (size_t)wave * DIM)
                                      : (X + (size_t)(wave - KCODE) * DIM);
    float4 v = *(const float4*)(row + lane * 4);
    float s = v.x * v.x + v.y * v.y + v.z * v.z + v.w * v.w;
#pragma unroll
    for (int off = 1; off < 64; off <<= 1) s += __shfl_xor(s, off);
    if (lane == 0) {
        if (wave < KCODE) wsq[wave] = s;
        else              xsq[wave - KCODE] = s;
    }
}

// ------------------------------------------------------------- argmin GEMM
// 128 tokens x (all 1024 codes in chunks of 128), BK=16, 256 threads, 8x8 microtile.
#define BM 128
#define BN 128
#define BK 16

__global__ __launch_bounds__(256) void argmin_kernel(
    const float* __restrict__ X, const float* __restrict__ W,
    const float* __restrict__ wsq, const float* __restrict__ xsq,
    int* __restrict__ idx_out)
{
    __shared__ float xs [BK][BM];   // transposed x panel
    __shared__ float wps[BK][BN];   // transposed w panel
    __shared__ float wsq_s[BN];

    const int tid  = threadIdx.x;
    const int tx   = tid & 15;
    const int ty   = tid >> 4;
    const int t0   = blockIdx.x * BM;
    const int trow = tid >> 1;            // 0..127 (staging row)
    const int khalf = (tid & 1) * 8;      // 0 or 8  (staging k half)

    float xsq_r[8];
#pragma unroll
    for (int i = 0; i < 8; ++i) xsq_r[i] = xsq[t0 + ty * 8 + i];

    float minv[8]; int mini[8];
#pragma unroll
    for (int i = 0; i < 8; ++i) { minv[i] = 3.402823466e+38f; mini[i] = 0; }

    for (int cc = 0; cc < KCODE / BN; ++cc) {
        const int c0 = cc * BN;
        float acc[8][8];
#pragma unroll
        for (int i = 0; i < 8; ++i)
#pragma unroll
            for (int j = 0; j < 8; ++j) acc[i][j] = 0.0f;

        for (int ks = 0; ks < DIM / BK; ++ks) {
            const int kb = ks * BK;
            __syncthreads();
            // stage: global -> LDS (transposed), coalesced 64B per row-pair
            {
                const float* xr = X + (size_t)(t0 + trow) * DIM + kb + khalf;
                float4 v0 = *(const float4*)xr;
                float4 v1 = *(const float4*)(xr + 4);
                xs[khalf + 0][trow] = v0.x; xs[khalf + 1][trow] = v0.y;
                xs[khalf + 2][trow] = v0.z; xs[khalf + 3][trow] = v0.w;
                xs[khalf + 4][trow] = v1.x; xs[khalf + 5][trow] = v1.y;
                xs[khalf + 6][trow] = v1.z; xs[khalf + 7][trow] = v1.w;
                const float* wr = W + (size_t)(c0 + trow) * DIM + kb + khalf;
                float4 u0 = *(const float4*)wr;
                float4 u1 = *(const float4*)(wr + 4);
                wps[khalf + 0][trow] = u0.x; wps[khalf + 1][trow] = u0.y;
                wps[khalf + 2][trow] = u0.z; wps[khalf + 3][trow] = u0.w;
                wps[khalf + 4][trow] = u1.x; wps[khalf + 5][trow] = u1.y;
                wps[khalf + 6][trow] = u1.z; wps[khalf + 7][trow] = u1.w;
                if (ks == 0 && tid < BN) wsq_s[tid] = wsq[c0 + tid];
            }
            __syncthreads();
#pragma unroll
            for (int kl = 0; kl < BK; ++kl) {
                float4 a0 = *(const float4*)&xs [kl][ty * 8];
                float4 a1 = *(const float4*)&xs [kl][ty * 8 + 4];
                float4 b0 = *(const float4*)&wps[kl][tx * 8];
                float4 b1 = *(const float4*)&wps[kl][tx * 8 + 4];
                float a[8] = {a0.x, a0.y, a0.z, a0.w, a1.x, a1.y, a1.z, a1.w};
                float b[8] = {b0.x, b0.y, b0.z, b0.w, b1.x, b1.y, b1.z, b1.w};
#pragma unroll
                for (int i = 0; i < 8; ++i)
#pragma unroll
                    for (int j = 0; j < 8; ++j)
                        acc[i][j] = fmaf(a[i], b[j], acc[i][j]);
            }
        }
        // scores: mirror numpy rounding  s = fl(fl(xsq+wsq) - fl(2*dot))
#pragma unroll
        for (int i = 0; i < 8; ++i) {
#pragma unroll
            for (int j = 0; j < 8; ++j) {
                float t1 = xsq_r[i] + wsq_s[tx * 8 + j];
                float s  = t1 - 2.0f * acc[i][j];
                int   c  = c0 + tx * 8 + j;
                if (s < minv[i]) { minv[i] = s; mini[i] = c; }
            }
        }
    }
    // reduce across the 16 tx lanes (consecutive lanes), lowest-index tie-break
#pragma unroll
    for (int i = 0; i < 8; ++i) {
#pragma unroll
        for (int off = 1; off < 16; off <<= 1) {
            float ov = __shfl_xor(minv[i], off);
            int   oi = __shfl_xor(mini[i], off);
            if (ov < minv[i] || (ov == minv[i] && oi < mini[i])) {
                minv[i] = ov; mini[i] = oi;
            }
        }
    }
    if (tx == 0) {
#pragma unroll
        for (int i = 0; i < 8; ++i) idx_out[t0 + ty * 8 + i] = mini[i];
    }
}

// --------------------------------------------- per-token epilogue: gather + scatter
// 64 threads per token (one float4 per thread along D).
__global__ __launch_bounds__(256) void epilogue_token(
    const float* __restrict__ X, const float* __restrict__ W,
    const int* __restrict__ idx, float* __restrict__ out,
    float* __restrict__ counts, float* __restrict__ dw, float* __restrict__ elat)
{
    int gid = blockIdx.x * 256 + threadIdx.x;   // < 65536*64
    int t = gid >> 6, q = gid & 63;
    int code = idx[t];
    float4 x4 = ((const float4*)X)[gid];
    float4 w4 = ((const float4*)W)[(size_t)code * 64 + q];
    ((float4*)(out + O_Q))[gid] = w4;           // quantized == quantized_raw (STE)
    float dx0 = w4.x - x4.x, dx1 = w4.y - x4.y, dx2 = w4.z - x4.z, dx3 = w4.w - x4.w;
    float e = dx0 * dx0 + dx1 * dx1 + dx2 * dx2 + dx3 * dx3;
    if (q == 0) {
        out[O_IDX + t] = (float)code;
        atomicAdd(&counts[code], 1.0f);
    }
    float* dwp = dw + (size_t)code * 256 + q * 4;
    atomicAdd(dwp + 0, x4.x);
    atomicAdd(dwp + 1, x4.y);
    atomicAdd(dwp + 2, x4.z);
    atomicAdd(dwp + 3, x4.w);
    // block-reduce e -> one atomic per block
#pragma unroll
    for (int off = 1; off < 64; off <<= 1) e += __shfl_xor(e, off);
    __shared__ float se[4];
    int lane = threadIdx.x & 63, wid = threadIdx.x >> 6;
    if (lane == 0) se[wid] = e;
    __syncthreads();
    if (threadIdx.x == 0) atomicAdd(elat, se[0] + se[1] + se[2] + se[3]);
}

// ------------------------------------------------ cluster EMA + loss + perplexity
__global__ __launch_bounds__(1024) void finalize_small(
    const float* __restrict__ ecs, const float* __restrict__ counts,
    const float* __restrict__ elat, float* __restrict__ out)
{
    int k = threadIdx.x;   // 1024 threads, one per code
    float cnt = counts[k];
    float nc = ecs[k] * (1.0f - MU_C) + MU_C * cnt;
    float p = cnt * (1.0f / 65536.0f);
    float h = p * logf(p + 1e-10f);
    float rn = nc, rh = h;
#pragma unroll
    for (int off = 1; off < 64; off <<= 1) {
        rn += __shfl_xor(rn, off);
        rh += __shfl_xor(rh, off);
    }
    __shared__ float sn[16], sh[16];
    int wid = k >> 6, lane = k & 63;
    if (lane == 0) { sn[wid] = rn; sh[wid] = rh; }
    __syncthreads();
    float n = 0.0f, H = 0.0f;
#pragma unroll
    for (int i = 0; i < 16; ++i) { n += sn[i]; H += sh[i]; }
    out[O_NC + k] = (nc + EPS_C) / (n + 1024.0f * EPS_C) * n;
    if (k == 0) {
        out[O_LOSS] = 0.25f * (elat[0] * (1.0f / 16777216.0f));  // * 2^-24 exact
        out[O_PERP] = expf(-H);
    }
}

// ------------------------------------------------ new_ema_w / new_embedding
// Scalar stores: O_NEW/O_EMB are 4-byte-misaligned for float4.
__global__ void finalize_embed(const float* __restrict__ ema_w,
                               const float* __restrict__ dw, float* __restrict__ out)
{
    int gid = blockIdx.x * blockDim.x + threadIdx.x;   // < 262144
    int k = gid >> 8;
    float ew = ema_w[gid] * (1.0f - MU_C) + MU_C * dw[gid];
    out[O_NEW + gid] = ew;
    out[O_EMB + gid] = ew / out[O_NC + k];
}

extern "C" void kernel_launch(void* const* d_in, const int* in_sizes, int n_in,
                              void* d_out, int out_size, void* d_ws, size_t ws_size,
                              hipStream_t stream) {
    const float* X     = (const float*)d_in[0];
    const float* W     = (const float*)d_in[1];
    const float* ema_w = (const float*)d_in[2];
    const float* ecs   = (const float*)d_in[3];
    float* out = (float*)d_out;
    float* ws  = (float*)d_ws;
    int*   idx    = (int*)d_ws;
    float* counts = ws + W_CNT;
    float* dw     = ws + W_DW;
    float* wsq    = ws + W_WSQ;
    float* xsq    = ws + W_XSQ;
    float* elat   = ws + W_ELAT;

    hipLaunchKernelGGL(zero_ws,        dim3(1029),  dim3(256),  0, stream, ws);
    hipLaunchKernelGGL(sumsq_kernel,   dim3(16640), dim3(256),  0, stream, W, X, wsq, xsq);
    hipLaunchKernelGGL(argmin_kernel,  dim3(512),   dim3(256),  0, stream, X, W, wsq, xsq, idx);
    hipLaunchKernelGGL(epilogue_token, dim3(16384), dim3(256),  0, stream, X, W, idx, out, counts, dw, elat);
    hipLaunchKernelGGL(finalize_small, dim3(1),     dim3(1024), 0, stream, ecs, counts, elat, out);
    hipLaunchKernelGGL(finalize_embed, dim3(1024),  dim3(256),  0, stream, ema_w, dw, out);
}